// Round 1
// baseline (1180.109 us; speedup 1.0000x reference)
//
#include <hip/hip_runtime.h>
#include <math.h>

#define H 1536
#define NH 12
#define NKV 2
#define HD 128
#define CTX 4096
#define NLAYERS 28
#define REP (NH / NKV)          // 6
#define EPS 1e-6f
#define SPAN 128
#define NSPLIT (CTX / SPAN)     // 32
#define SCALE 0.08838834764831845f   // 1/sqrt(128)

// ---------------------------------------------------------------------------
// K1: embedding gather + RMSNorm. 1 block x 256 threads.
// ---------------------------------------------------------------------------
__global__ void k_embed_norm(const int* __restrict__ ids,
                             const float* __restrict__ embed_w,
                             const float* __restrict__ ln_w,
                             float* __restrict__ ws_h,
                             float* __restrict__ ws_n) {
    __shared__ float red[4];
    int tid = threadIdx.x;
    int tok = ids[0];
    const float* row = embed_w + (size_t)tok * H;
    float hv[H / 256];
    float ss = 0.f;
#pragma unroll
    for (int i = 0; i < H / 256; ++i) {
        float v = row[tid + 256 * i];
        hv[i] = v;
        ss += v * v;
    }
    for (int off = 32; off; off >>= 1) ss += __shfl_down(ss, off, 64);
    int lane = tid & 63, wid = tid >> 6;
    if (lane == 0) red[wid] = ss;
    __syncthreads();
    if (tid == 0) {
        float t = red[0] + red[1] + red[2] + red[3];
        red[0] = rsqrtf(t / (float)H + EPS);
    }
    __syncthreads();
    float rs = red[0];
#pragma unroll
    for (int i = 0; i < H / 256; ++i) {
        int idx = tid + 256 * i;
        ws_h[idx] = hv[i];
        ws_n[idx] = hv[i] * rs * ln_w[idx];
    }
}

// ---------------------------------------------------------------------------
// K2: QKV matvec + bias. One wave per output row; 2048 rows -> 512 blocks.
// ---------------------------------------------------------------------------
__global__ void k_qkv(const float* __restrict__ n,
                      const float* __restrict__ qw, const float* __restrict__ qb,
                      const float* __restrict__ kw, const float* __restrict__ kb,
                      const float* __restrict__ vw, const float* __restrict__ vb,
                      float* __restrict__ q, float* __restrict__ k, float* __restrict__ v) {
    int wid = threadIdx.x >> 6;
    int lane = threadIdx.x & 63;
    int row = blockIdx.x * 4 + wid;   // 0..2047
    const float* w; const float* b; float* o; int r;
    if (row < H)            { w = qw; b = qb; o = q; r = row; }
    else if (row < H + 256) { w = kw; b = kb; o = k; r = row - H; }
    else                    { w = vw; b = vb; o = v; r = row - H - 256; }
    const float4* wr = (const float4*)(w + (size_t)r * H);
    const float4* nv = (const float4*)n;
    float acc = 0.f;
#pragma unroll
    for (int i = 0; i < H / 256; ++i) {   // 6 iters * 64 lanes * 4 = 1536
        float4 a = wr[lane + 64 * i];
        float4 x = nv[lane + 64 * i];
        acc += a.x * x.x + a.y * x.y + a.z * x.z + a.w * x.w;
    }
    for (int off = 32; off; off >>= 1) acc += __shfl_down(acc, off, 64);
    if (lane == 0) o[r] = acc + b[r];
}

// ---------------------------------------------------------------------------
// K3: RoPE on q (12 heads) and k (2 heads). 1 block x 896 threads.
// Each thread owns a (j, j+64) pair.
// ---------------------------------------------------------------------------
__global__ void k_rope(float* __restrict__ q, float* __restrict__ k,
                       const int* __restrict__ pos_ptr) {
    int t = threadIdx.x;              // 0..895
    double pos = (double)pos_ptr[0];
    int j = t & 63;
    double ang = pos * pow(1.0e6, -(double)(2 * j) / 128.0);
    float c = (float)cos(ang);
    float s = (float)sin(ang);
    float* base; int idx;
    if (t < NH * 64) { base = q; idx = (t >> 6) * HD + j; }
    else             { int tt = t - NH * 64; base = k; idx = (tt >> 6) * HD + j; }
    float x1 = base[idx], x2 = base[idx + 64];
    base[idx]      = x1 * c - x2 * s;
    base[idx + 64] = x2 * c + x1 * s;
}

// ---------------------------------------------------------------------------
// K4: flash-decode partials. Grid (NH, NSPLIT), 256 threads.
// Position == pos uses freshly computed (RoPE'd) k/v instead of cache.
// Partial record: [m, l, acc[128]] per (head, split).
// ---------------------------------------------------------------------------
__global__ void k_attn_part(const float* __restrict__ q,
                            const float* __restrict__ knew,
                            const float* __restrict__ vnew,
                            const float* __restrict__ kv_cache,
                            const int* __restrict__ pos_ptr,
                            float* __restrict__ part) {
    int head = blockIdx.x;
    int split = blockIdx.y;
    int tid = threadIdx.x;
    int pos = pos_ptr[0];
    int s0 = split * SPAN;
    float* pm = part + (size_t)(head * NSPLIT + split) * (HD + 2);
    int nv = min(SPAN, pos + 1 - s0);
    if (nv <= 0) {
        if (tid == 0) { pm[0] = -INFINITY; pm[1] = 0.f; }
        return;
    }
    int kvh = head / REP;
    const float* kcache = kv_cache + (size_t)kvh * CTX * HD;
    const float* vcache = kv_cache + ((size_t)(NLAYERS * NKV) + kvh) * CTX * HD;

    __shared__ float sc[SPAN];
    __shared__ float wred[4];
    __shared__ float accsh[HD];

    int lane = tid & 63, wid = tid >> 6;
    float2 q2 = ((const float2*)(q + head * HD))[lane];

    // phase 1: scores. wave per position.
    for (int p = wid; p < nv; p += 4) {
        int gp = s0 + p;
        const float2* krow = (const float2*)((gp == pos) ? (knew + kvh * HD)
                                                         : (kcache + (size_t)gp * HD));
        float2 kk = krow[lane];
        float partial = kk.x * q2.x + kk.y * q2.y;
        for (int off = 32; off; off >>= 1) partial += __shfl_down(partial, off, 64);
        if (lane == 0) sc[p] = partial * SCALE;
    }
    __syncthreads();                       // scores visible

    // phase 2: softmax stats
    float m = (tid < nv) ? sc[tid] : -INFINITY;
    for (int off = 32; off; off >>= 1) m = fmaxf(m, __shfl_down(m, off, 64));
    if (lane == 0) wred[wid] = m;
    __syncthreads();
    if (tid == 0) wred[0] = fmaxf(fmaxf(wred[0], wred[1]), fmaxf(wred[2], wred[3]));
    __syncthreads();
    m = wred[0];
    float e = (tid < nv) ? expf(sc[tid] - m) : 0.f;
    __syncthreads();                       // everyone has read sc & wred
    if (tid < nv) sc[tid] = e;
    float l = e;
    for (int off = 32; off; off >>= 1) l += __shfl_down(l, off, 64);
    if (lane == 0) wred[wid] = l;
    __syncthreads();                       // e-scores + wave sums visible
    float ltot = wred[0] + wred[1] + wred[2] + wred[3];

    // phase 3: weighted V accumulation. 2 groups of 128 threads over positions.
    int g = tid >> 7, d = tid & 127;
    float acc = 0.f;
    for (int p = g; p < nv; p += 2) {
        int gp = s0 + p;
        const float* vrow = (gp == pos) ? (vnew + kvh * HD) : (vcache + (size_t)gp * HD);
        acc = fmaf(sc[p], vrow[d], acc);
    }
    if (g == 1) accsh[d] = acc;
    __syncthreads();
    if (tid == 0) { pm[0] = m; pm[1] = ltot; }
    if (g == 0) pm[2 + d] = acc + accsh[d];
}

// ---------------------------------------------------------------------------
// K5: combine partials -> ctx[NH*HD]. Grid NH, 128 threads.
// ---------------------------------------------------------------------------
__global__ void k_combine(const float* __restrict__ part, float* __restrict__ ctx) {
    int head = blockIdx.x;
    int d = threadIdx.x;
    float M = -INFINITY;
    for (int s = 0; s < NSPLIT; ++s) {
        const float* pm = part + (size_t)(head * NSPLIT + s) * (HD + 2);
        if (pm[1] > 0.f) M = fmaxf(M, pm[0]);
    }
    float L = 0.f, acc = 0.f;
    for (int s = 0; s < NSPLIT; ++s) {
        const float* pm = part + (size_t)(head * NSPLIT + s) * (HD + 2);
        float l = pm[1];
        if (l > 0.f) {
            float w = expf(pm[0] - M);
            L += l * w;
            acc += w * pm[2 + d];
        }
    }
    ctx[head * HD + d] = acc / L;
}

// ---------------------------------------------------------------------------
// K6: O-projection + residual. One wave per row; 1536 rows -> 384 blocks.
// ---------------------------------------------------------------------------
__global__ void k_oproj(const float* __restrict__ ctx, const float* __restrict__ ow,
                        const float* __restrict__ h, float* __restrict__ out) {
    int wid = threadIdx.x >> 6;
    int lane = threadIdx.x & 63;
    int row = blockIdx.x * 4 + wid;   // 0..1535
    const float4* wr = (const float4*)(ow + (size_t)row * H);
    const float4* cv = (const float4*)ctx;
    float acc = 0.f;
#pragma unroll
    for (int i = 0; i < H / 256; ++i) {
        float4 a = wr[lane + 64 * i];
        float4 x = cv[lane + 64 * i];
        acc += a.x * x.x + a.y * x.y + a.z * x.z + a.w * x.w;
    }
    for (int off = 32; off; off >>= 1) acc += __shfl_down(acc, off, 64);
    if (lane == 0) out[row] = h[row] + acc;
}

// ---------------------------------------------------------------------------
extern "C" void kernel_launch(void* const* d_in, const int* in_sizes, int n_in,
                              void* d_out, int out_size, void* d_ws, size_t ws_size,
                              hipStream_t stream) {
    const int*   input_ids = (const int*)d_in[0];
    // d_in[1] position_ids, d_in[2] causal_mask: unused (pos drives everything)
    const int*   cur_pos   = (const int*)d_in[3];
    const float* embed_w   = (const float*)d_in[4];
    const float* ln_w      = (const float*)d_in[5];
    const float* q_w = (const float*)d_in[6],  *q_b = (const float*)d_in[7];
    const float* k_w = (const float*)d_in[8],  *k_b = (const float*)d_in[9];
    const float* v_w = (const float*)d_in[10], *v_b = (const float*)d_in[11];
    const float* o_w = (const float*)d_in[12];
    const float* kv  = (const float*)d_in[13];
    float* out = (float*)d_out;
    float* ws  = (float*)d_ws;

    float* ws_h    = ws;                // 1536
    float* ws_n    = ws_h + H;          // 1536
    float* ws_q    = ws_n + H;          // 1536
    float* ws_k    = ws_q + H;          // 256
    float* ws_v    = ws_k + 256;        // 256
    float* ws_ctx  = ws_v + 256;        // 1536
    float* ws_part = ws_ctx + H;        // 12*32*130 = 49920

    hipLaunchKernelGGL(k_embed_norm, dim3(1), dim3(256), 0, stream,
                       input_ids, embed_w, ln_w, ws_h, ws_n);
    hipLaunchKernelGGL(k_qkv, dim3(512), dim3(256), 0, stream,
                       ws_n, q_w, q_b, k_w, k_b, v_w, v_b, ws_q, ws_k, ws_v);
    hipLaunchKernelGGL(k_rope, dim3(1), dim3(896), 0, stream,
                       ws_q, ws_k, cur_pos);
    hipLaunchKernelGGL(k_attn_part, dim3(NH, NSPLIT), dim3(256), 0, stream,
                       ws_q, ws_k, ws_v, kv, cur_pos, ws_part);
    hipLaunchKernelGGL(k_combine, dim3(NH), dim3(HD), 0, stream,
                       ws_part, ws_ctx);
    hipLaunchKernelGGL(k_oproj, dim3(384), dim3(256), 0, stream,
                       ws_ctx, o_w, ws_h, out);
}